// Round 11
// baseline (186.083 us; speedup 1.0000x reference)
//
#include <hip/hip_runtime.h>
#include <math.h>

#define NB 4
#define C_ 256
#define NG 8
#define CPG 32
#define HW 4096
#define NH 4
#define HD 64
#define EPS 1e-5f
#define QSCALE 0.1803368801111204f  /* 0.125 * log2(e): folds 1/sqrt(64) and base-2 softmax */

typedef __attribute__((ext_vector_type(8))) short bf16x8_t;
typedef __attribute__((ext_vector_type(4))) float f32x4_t;
typedef const __attribute__((address_space(1))) void g_void;
typedef __attribute__((address_space(3))) void l_void;

__device__ __forceinline__ unsigned short f2bf(float f) {
    unsigned u = __float_as_uint(f);
    u += 0x7FFFu + ((u >> 16) & 1u);   // RNE
    return (unsigned short)(u >> 16);
}

// packed f32 pair -> 2x bf16 in one VALU op (RNE). No builtin on gfx950; asm.
__device__ __forceinline__ unsigned cvtpk(float lo, float hi) {
    unsigned r;
    asm("v_cvt_pk_bf16_f32 %0, %1, %2" : "=v"(r) : "v"(lo), "v"(hi));
    return r;
}

// Cross-lane 16/32-row exchange between two registers (builtin = hazard-safe).
__device__ __forceinline__ void plswap16(unsigned &a, unsigned &b) {
#if __has_builtin(__builtin_amdgcn_permlane16_swap)
    auto r = __builtin_amdgcn_permlane16_swap(a, b, false, false);
    a = r[0]; b = r[1];
#else
    unsigned as = (unsigned)__shfl_xor((int)a, 16);
    unsigned bs = (unsigned)__shfl_xor((int)b, 16);
    bool hi = (threadIdx.x & 16) != 0;
    unsigned na = hi ? bs : a;
    unsigned nb = hi ? b : as;
    a = na; b = nb;
#endif
}
__device__ __forceinline__ void plswap32(unsigned &a, unsigned &b) {
#if __has_builtin(__builtin_amdgcn_permlane32_swap)
    auto r = __builtin_amdgcn_permlane32_swap(a, b, false, false);
    a = r[0]; b = r[1];
#else
    unsigned as = (unsigned)__shfl_xor((int)a, 32);
    unsigned bs = (unsigned)__shfl_xor((int)b, 32);
    bool hi = (threadIdx.x & 32) != 0;
    unsigned na = hi ? bs : a;
    unsigned nb = hi ? b : as;
    a = na; b = nb;
#endif
}

// ---------------- GroupNorm stats phase A + fused weight conversion ----------------
// Blocks 0..1023: per-(b,g) chunk stats. Blocks 1024..1279: w_qkv/w_proj -> bf16.
__global__ __launch_bounds__(256) void gn_stats_wconv_k(const float* __restrict__ x,
                                                        float2* __restrict__ part,
                                                        const float* __restrict__ wq,
                                                        const float* __restrict__ wp,
                                                        unsigned short* __restrict__ wt,
                                                        unsigned short* __restrict__ wpt) {
    if (blockIdx.x >= 1024) {
        int i4 = (blockIdx.x - 1024) * 256 + threadIdx.x;   // 0..65535 float4 groups
        const float* src;
        unsigned short* dst;
        int off;
        if (i4 < 49152) { src = wq; dst = wt; off = i4 * 4; }
        else            { src = wp; dst = wpt; off = (i4 - 49152) * 4; }
        float4 v = *(const float4*)(src + off);
        ushort4 o;
        o.x = f2bf(v.x); o.y = f2bf(v.y); o.z = f2bf(v.z); o.w = f2bf(v.w);
        *(ushort4*)(dst + off) = o;
        return;
    }
    int bg = blockIdx.x >> 5, ch = blockIdx.x & 31;
    const float4* base = (const float4*)(x + (size_t)bg * CPG * HW + ch * 4096);
    float s = 0.f, ss = 0.f;
    #pragma unroll
    for (int i = threadIdx.x; i < 1024; i += 256) {
        float4 v = base[i];
        s  += v.x + v.y + v.z + v.w;
        ss += v.x*v.x + v.y*v.y + v.z*v.z + v.w*v.w;
    }
    #pragma unroll
    for (int off = 32; off > 0; off >>= 1) {
        s  += __shfl_down(s, off);
        ss += __shfl_down(ss, off);
    }
    __shared__ float rs[4], rss[4];
    int wv = threadIdx.x >> 6;
    if ((threadIdx.x & 63) == 0) { rs[wv] = s; rss[wv] = ss; }
    __syncthreads();
    if (threadIdx.x == 0)
        part[blockIdx.x] = make_float2(rs[0]+rs[1]+rs[2]+rs[3], rss[0]+rss[1]+rss[2]+rss[3]);
}

// ---------------- GroupNorm apply + transpose -> ht[b][p][c] bf16 (fin fused) ----------------
__global__ __launch_bounds__(256) void gn_apply_t_k(const float* __restrict__ x,
                                                    const float* __restrict__ gamma,
                                                    const float* __restrict__ beta,
                                                    const float2* __restrict__ part,
                                                    unsigned short* __restrict__ ht) {
    __shared__ unsigned short T[64 * 66];
    __shared__ float sstat[4];   // mean0, rstd0, mean1, rstd1
    int b = blockIdx.z, c0 = blockIdx.y * 64, p0 = blockIdx.x * 64;
    int t = threadIdx.x;
    if (t < 64) {
        int half = t >> 5;                       // group within this c-tile
        int g = b * NG + (c0 >> 5) + half;
        float2 v = part[g * 32 + (t & 31)];
        float s = v.x, ss = v.y;
        #pragma unroll
        for (int off = 16; off > 0; off >>= 1) {
            s  += __shfl_xor(s, off);
            ss += __shfl_xor(ss, off);
        }
        if ((t & 31) == 0) {
            const float inv = 1.f / (float)(CPG * HW);
            float mean = s * inv;
            float var  = ss * inv - mean * mean;
            sstat[half * 2]     = mean;
            sstat[half * 2 + 1] = rsqrtf(var + EPS);
        }
    }
    __syncthreads();
    int cr = t >> 4, pc = t & 15;
    #pragma unroll
    for (int cp = 0; cp < 4; cp++) {
        int c = c0 + cp * 16 + cr;
        int gl = (cp * 16 + cr) >> 5;
        float mean = sstat[gl * 2], rstd = sstat[gl * 2 + 1];
        float sc = gamma[c] * rstd;
        float sh = beta[c] - mean * sc;
        float4 v = *(const float4*)(x + ((size_t)(b * C_ + c)) * HW + p0 + pc * 4);
        int cc = cp * 16 + cr;
        T[(pc*4 + 0) * 66 + cc] = f2bf(v.x*sc + sh);
        T[(pc*4 + 1) * 66 + cc] = f2bf(v.y*sc + sh);
        T[(pc*4 + 2) * 66 + cc] = f2bf(v.z*sc + sh);
        T[(pc*4 + 3) * 66 + cc] = f2bf(v.w*sc + sh);
    }
    __syncthreads();
    int p = t >> 2, cq = t & 3;
    const unsigned* rp = (const unsigned*)(T + p * 66 + cq * 16);
    unsigned short* dst = ht + ((size_t)b * HW + p0 + p) * 256 + c0 + cq * 16;
    *(uint4*)dst       = make_uint4(rp[0], rp[1], rp[2], rp[3]);
    *(uint4*)(dst + 8) = make_uint4(rp[4], rp[5], rp[6], rp[7]);
}

// ---------------- QKV GEMM v2: 128x128 tile, ring-3 LDS staging, counted vmcnt ----------------
// r19: Q/K epilogue also routed through LDS (pitch 130) -> fully coalesced uint4
// row writes (was 8B/lane at 128B stride = 64-line scatter per wave-store).
__global__ __launch_bounds__(256) void gemm_qkv_mfma_k(const unsigned short* __restrict__ wt,
                                                       const unsigned short* __restrict__ ht,
                                                       const float* __restrict__ bias,
                                                       unsigned short* __restrict__ qt,
                                                       unsigned short* __restrict__ kt,
                                                       unsigned short* __restrict__ vv) {
    __shared__ __align__(16) unsigned short smem[24576];   // ring-3 x (A 8KB + B 8KB) = 48KB
    int t = threadIdx.x, wave = t >> 6, lane = t & 63, quad = lane >> 4, l16 = lane & 15;
    int mq = wave & 1, pq = wave >> 1;
    int L = blockIdx.x;
    int W = (L & 7) * 96 + (L >> 3);          // 768 % 8 == 0: bijective XCD swizzle
    int b = W / 192;
    int rem = W - b * 192;
    int px = rem / 6;
    int my = rem - px * 6;
    const char* Ag = (const char*)(wt + (size_t)(my * 128) * 256);
    const char* Bg = (const char*)(ht + ((size_t)b * HW + px * 128) * 256);

    int soff[2], lbs[2];
    #pragma unroll
    for (int n = 0; n < 2; n++) {
        int s = n * 256 + t;
        int row = s >> 2, c = (s & 3) ^ (row & 3);
        soff[n] = row * 512 + c * 16;          // bytes (global row = 256 bf16 = 512B)
        lbs[n]  = s * 8;                       // ushort idx (slot s -> s*16 bytes)
    }

    auto STAGE = [&](int kc, int buf) {
        const char* a  = Ag + kc * 64;
        const char* bb = Bg + kc * 64;
        #pragma unroll
        for (int n = 0; n < 2; n++) {
            __builtin_amdgcn_global_load_lds((g_void*)(a  + soff[n]), (l_void*)(smem + buf * 8192 + lbs[n]), 16, 0, 0);
            __builtin_amdgcn_global_load_lds((g_void*)(bb + soff[n]), (l_void*)(smem + buf * 8192 + 4096 + lbs[n]), 16, 0, 0);
        }
    };

    f32x4_t acc[4][4];
    const f32x4_t zz = {0.f, 0.f, 0.f, 0.f};
    #pragma unroll
    for (int i = 0; i < 4; i++)
        #pragma unroll
        for (int j = 0; j < 4; j++) acc[i][j] = zz;

    STAGE(0, 0);
    STAGE(1, 1);
    int cur = 0;
    for (int kc = 0; kc < 8; kc++) {
        if (kc < 7) asm volatile("s_waitcnt vmcnt(4)" ::: "memory");
        else        asm volatile("s_waitcnt vmcnt(0)" ::: "memory");
        asm volatile("s_barrier" ::: "memory");
        if (kc + 2 < 8) { int nb = cur + 2; if (nb >= 3) nb -= 3; STAGE(kc + 2, nb); }
        const unsigned short* Ac = smem + cur * 8192;
        const unsigned short* Bc = smem + cur * 8192 + 4096;
        bf16x8_t af[4], bfr[4];
        #pragma unroll
        for (int mi = 0; mi < 4; mi++) {
            int R = mq * 64 + mi * 16 + l16;
            af[mi] = *(const bf16x8_t*)&Ac[(R * 4 + (quad ^ (R & 3))) * 8];
        }
        #pragma unroll
        for (int pi = 0; pi < 4; pi++) {
            int P = pq * 64 + pi * 16 + l16;
            bfr[pi] = *(const bf16x8_t*)&Bc[(P * 4 + (quad ^ (P & 3))) * 8];
        }
        __builtin_amdgcn_s_setprio(1);
        #pragma unroll
        for (int mi = 0; mi < 4; mi++)
            #pragma unroll
            for (int pi = 0; pi < 4; pi++)
                acc[mi][pi] = __builtin_amdgcn_mfma_f32_16x16x32_bf16(af[mi], bfr[pi], acc[mi][pi], 0, 0, 0);
        __builtin_amdgcn_s_setprio(0);
        cur = (cur + 1 == 3) ? 0 : cur + 1;
    }

    int sec = my >> 1;                          // 0=Q 1=K 2=V
    if (sec < 2) {
        float scl = (sec == 0) ? QSCALE : 1.f;
        // stage [128 p][128 m] in LDS (pitch 130), cvtpk-paired dword writes
        // (lane stride 65 dwords -> conflict-free), then coalesced uint4 row writes:
        // 8 threads cover one full 128B output row.
        __syncthreads();                        // ring buffers fully consumed
        unsigned* Tw = (unsigned*)smem;
        #pragma unroll
        for (int mi = 0; mi < 4; mi++) {
            int mh = mq * 32 + mi * 8 + quad * 2;   // m_local/2
            int mg = my * 128 + mq * 64 + mi * 16 + quad * 4;
            #pragma unroll
            for (int pi = 0; pi < 4; pi++) {
                int pl = pq * 64 + pi * 16 + l16;
                Tw[pl * 65 + mh]     = cvtpk((acc[mi][pi][0] + bias[mg + 0]) * scl,
                                             (acc[mi][pi][1] + bias[mg + 1]) * scl);
                Tw[pl * 65 + mh + 1] = cvtpk((acc[mi][pi][2] + bias[mg + 2]) * scl,
                                             (acc[mi][pi][3] + bias[mg + 3]) * scl);
            }
        }
        __syncthreads();
        int row = t >> 3, chunk = t & 7;        // 32 rows/pass, 8 x 16B chunks = 128B row
        #pragma unroll
        for (int h2 = 0; h2 < 2; h2++) {
            int hh = ((my & 1) << 1) | h2;
            unsigned short* dst = ((sec == 0) ? qt : kt) + (size_t)(b * NH + hh) * HW * 64;
            #pragma unroll
            for (int rr = 0; rr < 4; rr++) {
                int pl = rr * 32 + row;
                const unsigned* rp = Tw + pl * 65 + h2 * 32 + chunk * 4;
                *(uint4*)(dst + (size_t)(px * 128 + pl) * 64 + chunk * 8) =
                    make_uint4(rp[0], rp[1], rp[2], rp[3]);
            }
        }
    } else {
        // V: [128 d][128 p] LDS transpose (pitch 130), then coalesced row writes
        __syncthreads();                        // ring buffers fully consumed
        unsigned short* T = smem;
        #pragma unroll
        for (int mi = 0; mi < 4; mi++) {
            int dT = mq * 64 + mi * 16 + quad * 4;
            int mg = my * 128 + dT;
            #pragma unroll
            for (int pi = 0; pi < 4; pi++) {
                int pl = pq * 64 + pi * 16 + l16;
                #pragma unroll
                for (int r = 0; r < 4; r++)
                    T[(dT + r) * 130 + pl] = f2bf(acc[mi][pi][r] + bias[mg + r]);
            }
        }
        __syncthreads();
        int dT = t >> 1, half = t & 1;
        const unsigned* rp = (const unsigned*)(T + dT * 130 + half * 64);
        unsigned short* dd = vv + ((size_t)(b * 256 + (my & 1) * 128 + dT)) * HW + px * 128 + half * 64;
        #pragma unroll
        for (int q8 = 0; q8 < 8; q8++)
            *(uint4*)(dd + q8 * 8) = make_uint4(rp[q8*4+0], rp[q8*4+1], rp[q8*4+2], rp[q8*4+3]);
    }
}

// ---------------- proj GEMM v2: 128x128 tile, ring-3 LDS staging (same skeleton) ----------------
// out[b][256,4096] = wpt[256,256] . ao[b][4096,256]^T + bias + x. Grid 256 blocks.
__global__ __launch_bounds__(256) void gemm_proj_mfma_k(const unsigned short* __restrict__ wpt,
                                                        const unsigned short* __restrict__ ao,
                                                        const float* __restrict__ bias,
                                                        const float* __restrict__ x,
                                                        float* __restrict__ out) {
    __shared__ __align__(16) unsigned short smem[24576];   // ring-3 x (A 8KB + B 8KB) = 48KB
    int t = threadIdx.x, wave = t >> 6, lane = t & 63, quad = lane >> 4, l16 = lane & 15;
    int mq = wave & 1, pq = wave >> 1;
    int L = blockIdx.x;
    int W = (L & 7) * 32 + (L >> 3);          // 256 % 8 == 0: bijective XCD swizzle
    int b = W >> 6;
    int rem = W & 63;
    int px = rem >> 1;
    int my = rem & 1;
    const char* Ag = (const char*)(wpt + (size_t)(my * 128) * 256);
    const char* Bg = (const char*)(ao + ((size_t)b * HW + px * 128) * 256);

    int soff[2], lbs[2];
    #pragma unroll
    for (int n = 0; n < 2; n++) {
        int s = n * 256 + t;
        int row = s >> 2, c = (s & 3) ^ (row & 3);
        soff[n] = row * 512 + c * 16;
        lbs[n]  = s * 8;
    }

    auto STAGE = [&](int kc, int buf) {
        const char* a  = Ag + kc * 64;
        const char* bb = Bg + kc * 64;
        #pragma unroll
        for (int n = 0; n < 2; n++) {
            __builtin_amdgcn_global_load_lds((g_void*)(a  + soff[n]), (l_void*)(smem + buf * 8192 + lbs[n]), 16, 0, 0);
            __builtin_amdgcn_global_load_lds((g_void*)(bb + soff[n]), (l_void*)(smem + buf * 8192 + 4096 + lbs[n]), 16, 0, 0);
        }
    };

    f32x4_t acc[4][4];
    const f32x4_t zz = {0.f, 0.f, 0.f, 0.f};
    #pragma unroll
    for (int i = 0; i < 4; i++)
        #pragma unroll
        for (int j = 0; j < 4; j++) acc[i][j] = zz;

    STAGE(0, 0);
    STAGE(1, 1);
    int cur = 0;
    for (int kc = 0; kc < 8; kc++) {
        if (kc < 7) asm volatile("s_waitcnt vmcnt(4)" ::: "memory");
        else        asm volatile("s_waitcnt vmcnt(0)" ::: "memory");
        asm volatile("s_barrier" ::: "memory");
        if (kc + 2 < 8) { int nb = cur + 2; if (nb >= 3) nb -= 3; STAGE(kc + 2, nb); }
        const unsigned short* Ac = smem + cur * 8192;
        const unsigned short* Bc = smem + cur * 8192 + 4096;
        bf16x8_t af[4], bfr[4];
        #pragma unroll
        for (int mi = 0; mi < 4; mi++) {
            int R = mq * 64 + mi * 16 + l16;
            af[mi] = *(const bf16x8_t*)&Ac[(R * 4 + (quad ^ (R & 3))) * 8];
        }
        #pragma unroll
        for (int pi = 0; pi < 4; pi++) {
            int P = pq * 64 + pi * 16 + l16;
            bfr[pi] = *(const bf16x8_t*)&Bc[(P * 4 + (quad ^ (P & 3))) * 8];
        }
        __builtin_amdgcn_s_setprio(1);
        #pragma unroll
        for (int mi = 0; mi < 4; mi++)
            #pragma unroll
            for (int pi = 0; pi < 4; pi++)
                acc[mi][pi] = __builtin_amdgcn_mfma_f32_16x16x32_bf16(af[mi], bfr[pi], acc[mi][pi], 0, 0, 0);
        __builtin_amdgcn_s_setprio(0);
        cur = (cur + 1 == 3) ? 0 : cur + 1;
    }

    // epilogue: acc + bias + residual x -> fp32 out (lanes contiguous in p: coalesced)
    #pragma unroll
    for (int mi = 0; mi < 4; mi++)
        #pragma unroll
        for (int pi = 0; pi < 4; pi++) {
            int p = px * 128 + pq * 64 + pi * 16 + l16;
            #pragma unroll
            for (int r = 0; r < 4; r++) {
                int m = my * 128 + mq * 64 + mi * 16 + quad * 4 + r;
                size_t off = (size_t)(b * C_ + m) * HW + p;
                out[off] = acc[mi][pi][r] + bias[m] + x[off];
            }
        }
}

// ---------------- Flash attention (unchanged from R8: bounded-score softmax) ----------------
__global__ __launch_bounds__(512) __attribute__((amdgpu_waves_per_eu(2, 8)))
void attn_k(const unsigned short* __restrict__ qt,
            const unsigned short* __restrict__ kt,
            const unsigned short* __restrict__ vv,
            unsigned short* __restrict__ ao) {
    __shared__ __align__(16) unsigned short smem[24576];
    int t = threadIdx.x;
    int wave = t >> 6, lane = t & 63, quad = lane >> 4, l16 = lane & 15;
    int iw = wave & 3, jw = wave >> 2;
    int L = blockIdx.x;
    int W = (L & 7) * 64 + (L >> 3);
    int i0 = (W & 31) * 128;
    int hh = (W >> 5) & 3;
    int b  = W >> 7;
    const unsigned short* qb = qt + (size_t)(b * NH + hh) * HW * 64;
    const char* kbp = (const char*)(kt + (size_t)(b * NH + hh) * HW * 64);
    const char* vbp = (const char*)(vv + (size_t)(b * NH + hh) * 64 * HW);

    bf16x8_t qf[2][2];
    #pragma unroll
    for (int mi = 0; mi < 2; mi++)
        #pragma unroll
        for (int kc = 0; kc < 2; kc++)
            qf[mi][kc] = *(const bf16x8_t*)(qb + (size_t)(i0 + iw * 32 + mi * 16 + l16) * 64 + kc * 32 + quad * 8);

    f32x4_t oacc[4][2], osum[2];
    const f32x4_t zz = {0.f, 0.f, 0.f, 0.f};
    #pragma unroll
    for (int dt = 0; dt < 4; dt++) { oacc[dt][0] = zz; oacc[dt][1] = zz; }
    osum[0] = zz; osum[1] = zz;

    bf16x8_t ones;
    #pragma unroll
    for (int e = 0; e < 8; e++) ones[e] = (short)0x3F80;   // bf16 1.0

    bool isK = (jw == 0);
    int soff[2], lbase[2];
    #pragma unroll
    for (int n = 0; n < 2; n++) {
        int s = (iw * 2 + n) * 64 + lane;
        int row = s >> 3;
        int c = (s & 7) ^ (row & 7);
        soff[n] = isK ? (row * 128 + c * 16) : (row * (HW * 2) + c * 16);
        lbase[n] = (isK ? 0 : 12288) + (iw * 2 + n) * 512;
    }
    const char* gsrc0 = isK ? kbp : vbp;
    int tstride = isK ? 8192 : 128;

    auto STAGE = [&](int tile, int buf) {
        const char* g = gsrc0 + (size_t)tile * tstride;
        #pragma unroll
        for (int n = 0; n < 2; n++)
            __builtin_amdgcn_global_load_lds((g_void*)(g + soff[n]),
                                             (l_void*)(smem + buf * 4096 + lbase[n]), 16, 0, 0);
    };

    STAGE(0, 0);
    STAGE(1, 1);

    int cur = 0;
    for (int jt = 0; jt < 64; jt++) {
        if (jt < 63) asm volatile("s_waitcnt vmcnt(2)" ::: "memory");
        else         asm volatile("s_waitcnt vmcnt(0)" ::: "memory");
        asm volatile("s_barrier" ::: "memory");
        if (jt + 2 < 64) {
            int nb = cur + 2; if (nb >= 3) nb -= 3;
            STAGE(jt + 2, nb);
        }
        const unsigned short* Kc = smem + cur * 4096;
        const unsigned short* Vc = smem + 12288 + cur * 4096;

        f32x4_t sacc[2][2];
        sacc[0][0] = zz; sacc[0][1] = zz; sacc[1][0] = zz; sacc[1][1] = zz;
        __builtin_amdgcn_s_setprio(1);
        #pragma unroll
        for (int nj = 0; nj < 2; nj++) {
            int j = jw * 32 + nj * 16 + l16;
            int rb = j * 8;
            bf16x8_t kf0 = *(const bf16x8_t*)&Kc[(rb + ((quad    ) ^ (j & 7))) * 8];
            bf16x8_t kf1 = *(const bf16x8_t*)&Kc[(rb + ((4 + quad) ^ (j & 7))) * 8];
            #pragma unroll
            for (int mi = 0; mi < 2; mi++) {
                sacc[mi][nj] = __builtin_amdgcn_mfma_f32_16x16x32_bf16(kf0, qf[mi][0], sacc[mi][nj], 0, 0, 0);
                sacc[mi][nj] = __builtin_amdgcn_mfma_f32_16x16x32_bf16(kf1, qf[mi][1], sacc[mi][nj], 0, 0, 0);
            }
        }
        __builtin_amdgcn_s_setprio(0);

        bf16x8_t pf[2];
        #pragma unroll
        for (int mi = 0; mi < 2; mi++) {
            #pragma unroll
            for (int nj = 0; nj < 2; nj++)
                #pragma unroll
                for (int r = 0; r < 4; r++)
                    sacc[mi][nj][r] = __builtin_amdgcn_exp2f(sacc[mi][nj][r]);

            unsigned lo0 = cvtpk(sacc[mi][0][0], sacc[mi][0][1]);
            unsigned hi0 = cvtpk(sacc[mi][0][2], sacc[mi][0][3]);
            unsigned lo1 = cvtpk(sacc[mi][1][0], sacc[mi][1][1]);
            unsigned hi1 = cvtpk(sacc[mi][1][2], sacc[mi][1][3]);
            plswap32(lo0, lo1); plswap16(lo0, lo1);  // lo0=d0, lo1=d2
            plswap32(hi0, hi1); plswap16(hi0, hi1);  // hi0=d1, hi1=d3
            union { unsigned u[4]; bf16x8_t v8; } pu;
            pu.u[0] = lo0; pu.u[1] = hi0; pu.u[2] = lo1; pu.u[3] = hi1;
            pf[mi] = pu.v8;
        }

        __builtin_amdgcn_s_setprio(1);
        #pragma unroll
        for (int dt = 0; dt < 4; dt++) {
            int d = dt * 16 + l16;
            bf16x8_t vf = *(const bf16x8_t*)&Vc[(d * 8 + ((jw * 4 + quad) ^ (d & 7))) * 8];
            oacc[dt][0] = __builtin_amdgcn_mfma_f32_16x16x32_bf16(vf, pf[0], oacc[dt][0], 0, 0, 0);
            oacc[dt][1] = __builtin_amdgcn_mfma_f32_16x16x32_bf16(vf, pf[1], oacc[dt][1], 0, 0, 0);
        }
        osum[0] = __builtin_amdgcn_mfma_f32_16x16x32_bf16(ones, pf[0], osum[0], 0, 0, 0);
        osum[1] = __builtin_amdgcn_mfma_f32_16x16x32_bf16(ones, pf[1], osum[1], 0, 0, 0);
        __builtin_amdgcn_s_setprio(0);

        cur = (cur + 1 == 3) ? 0 : cur + 1;
    }

    __syncthreads();
    float* Obuf = (float*)smem;                // [128 rows][pitch 68]: cols 0..63 = d, 64 = l
    if (jw == 1) {
        #pragma unroll
        for (int mi = 0; mi < 2; mi++) {
            int R = iw * 32 + mi * 16 + l16;
            #pragma unroll
            for (int dt = 0; dt < 4; dt++)
                *(f32x4_t*)&Obuf[R * 68 + dt * 16 + quad * 4] = oacc[dt][mi];
            if (quad == 0)
                Obuf[R * 68 + 64] = osum[mi][0];
        }
    }
    __syncthreads();
    if (jw == 0) {
        #pragma unroll
        for (int mi = 0; mi < 2; mi++) {
            int R = iw * 32 + mi * 16 + l16;
            float l  = osum[mi][0] + Obuf[R * 68 + 64];
            float c0 = 1.f / l;
            unsigned short* dst = ao + ((size_t)b * HW + i0 + R) * 256 + hh * 64 + quad * 4;
            #pragma unroll
            for (int dt = 0; dt < 4; dt++) {
                f32x4_t o1 = *(const f32x4_t*)&Obuf[R * 68 + dt * 16 + quad * 4];
                unsigned w0 = cvtpk((oacc[dt][mi][0] + o1[0]) * c0,
                                    (oacc[dt][mi][1] + o1[1]) * c0);
                unsigned w1 = cvtpk((oacc[dt][mi][2] + o1[2]) * c0,
                                    (oacc[dt][mi][3] + o1[3]) * c0);
                *(uint2*)(dst + dt * 16) = make_uint2(w0, w1);
            }
        }
    }
}

extern "C" void kernel_launch(void* const* d_in, const int* in_sizes, int n_in,
                              void* d_out, int out_size, void* d_ws, size_t ws_size,
                              hipStream_t stream) {
    const float* x      = (const float*)d_in[0];
    const float* gamma  = (const float*)d_in[1];
    const float* beta   = (const float*)d_in[2];
    const float* w_qkv  = (const float*)d_in[3];
    const float* b_qkv  = (const float*)d_in[4];
    const float* w_proj = (const float*)d_in[5];
    const float* b_proj = (const float*)d_in[6];
    float* out = (float*)d_out;

    // ws: stats 256f | part 1024 float2 | ht,qt,kt,vv,ao (5 x 4M ushorts = 40MB) | wt,wpt bf16
    float* stats = (float*)d_ws;
    float2* part = (float2*)(stats + 256);
    unsigned short* ht  = (unsigned short*)(stats + 256 + 2048);
    unsigned short* qt  = ht + (size_t)4194304;
    unsigned short* kt  = qt + (size_t)4194304;
    unsigned short* vv  = kt + (size_t)4194304;
    unsigned short* ao  = vv + (size_t)4194304;
    unsigned short* wt  = ao + (size_t)4194304;
    unsigned short* wpt = wt + 196608;

    gn_stats_wconv_k<<<1280, 256, 0, stream>>>(x, part, w_qkv, w_proj, wt, wpt);
    gn_apply_t_k<<<dim3(64, 4, NB), 256, 0, stream>>>(x, gamma, beta, part, ht);
    gemm_qkv_mfma_k<<<768, 256, 0, stream>>>(wt, ht, b_qkv, qt, kt, vv);
    attn_k<<<512, 512, 0, stream>>>(qt, kt, vv, ao);
    gemm_proj_mfma_k<<<256, 256, 0, stream>>>(wpt, ao, b_proj, x, out);
}

// Round 12
// 183.505 us; speedup vs baseline: 1.0140x; 1.0140x over previous
//
#include <hip/hip_runtime.h>
#include <math.h>

#define NB 4
#define C_ 256
#define NG 8
#define CPG 32
#define HW 4096
#define NH 4
#define HD 64
#define EPS 1e-5f
#define QSCALE 0.1803368801111204f  /* 0.125 * log2(e): folds 1/sqrt(64) and base-2 softmax */

typedef __attribute__((ext_vector_type(8))) short bf16x8_t;
typedef __attribute__((ext_vector_type(4))) float f32x4_t;
typedef const __attribute__((address_space(1))) void g_void;
typedef __attribute__((address_space(3))) void l_void;

__device__ __forceinline__ unsigned short f2bf(float f) {
    unsigned u = __float_as_uint(f);
    u += 0x7FFFu + ((u >> 16) & 1u);   // RNE
    return (unsigned short)(u >> 16);
}

// packed f32 pair -> 2x bf16 in one VALU op (RNE). No builtin on gfx950; asm.
__device__ __forceinline__ unsigned cvtpk(float lo, float hi) {
    unsigned r;
    asm("v_cvt_pk_bf16_f32 %0, %1, %2" : "=v"(r) : "v"(lo), "v"(hi));
    return r;
}

// Cross-lane 16/32-row exchange between two registers (builtin = hazard-safe).
__device__ __forceinline__ void plswap16(unsigned &a, unsigned &b) {
#if __has_builtin(__builtin_amdgcn_permlane16_swap)
    auto r = __builtin_amdgcn_permlane16_swap(a, b, false, false);
    a = r[0]; b = r[1];
#else
    unsigned as = (unsigned)__shfl_xor((int)a, 16);
    unsigned bs = (unsigned)__shfl_xor((int)b, 16);
    bool hi = (threadIdx.x & 16) != 0;
    unsigned na = hi ? bs : a;
    unsigned nb = hi ? b : as;
    a = na; b = nb;
#endif
}
__device__ __forceinline__ void plswap32(unsigned &a, unsigned &b) {
#if __has_builtin(__builtin_amdgcn_permlane32_swap)
    auto r = __builtin_amdgcn_permlane32_swap(a, b, false, false);
    a = r[0]; b = r[1];
#else
    unsigned as = (unsigned)__shfl_xor((int)a, 32);
    unsigned bs = (unsigned)__shfl_xor((int)b, 32);
    bool hi = (threadIdx.x & 32) != 0;
    unsigned na = hi ? bs : a;
    unsigned nb = hi ? b : as;
    a = na; b = nb;
#endif
}

// ---------------- GroupNorm stats phase A + fused weight conversion ----------------
// Blocks 0..1023: per-(b,g) chunk stats. Blocks 1024..1279: w_qkv/w_proj -> bf16.
__global__ __launch_bounds__(256) void gn_stats_wconv_k(const float* __restrict__ x,
                                                        float2* __restrict__ part,
                                                        const float* __restrict__ wq,
                                                        const float* __restrict__ wp,
                                                        unsigned short* __restrict__ wt,
                                                        unsigned short* __restrict__ wpt) {
    if (blockIdx.x >= 1024) {
        int i4 = (blockIdx.x - 1024) * 256 + threadIdx.x;   // 0..65535 float4 groups
        const float* src;
        unsigned short* dst;
        int off;
        if (i4 < 49152) { src = wq; dst = wt; off = i4 * 4; }
        else            { src = wp; dst = wpt; off = (i4 - 49152) * 4; }
        float4 v = *(const float4*)(src + off);
        ushort4 o;
        o.x = f2bf(v.x); o.y = f2bf(v.y); o.z = f2bf(v.z); o.w = f2bf(v.w);
        *(ushort4*)(dst + off) = o;
        return;
    }
    int bg = blockIdx.x >> 5, ch = blockIdx.x & 31;
    const float4* base = (const float4*)(x + (size_t)bg * CPG * HW + ch * 4096);
    float s = 0.f, ss = 0.f;
    #pragma unroll
    for (int i = threadIdx.x; i < 1024; i += 256) {
        float4 v = base[i];
        s  += v.x + v.y + v.z + v.w;
        ss += v.x*v.x + v.y*v.y + v.z*v.z + v.w*v.w;
    }
    #pragma unroll
    for (int off = 32; off > 0; off >>= 1) {
        s  += __shfl_down(s, off);
        ss += __shfl_down(ss, off);
    }
    __shared__ float rs[4], rss[4];
    int wv = threadIdx.x >> 6;
    if ((threadIdx.x & 63) == 0) { rs[wv] = s; rss[wv] = ss; }
    __syncthreads();
    if (threadIdx.x == 0)
        part[blockIdx.x] = make_float2(rs[0]+rs[1]+rs[2]+rs[3], rss[0]+rss[1]+rss[2]+rss[3]);
}

// ---------------- GroupNorm apply + transpose -> ht[b][p][c] bf16 (fin fused) ----------------
__global__ __launch_bounds__(256) void gn_apply_t_k(const float* __restrict__ x,
                                                    const float* __restrict__ gamma,
                                                    const float* __restrict__ beta,
                                                    const float2* __restrict__ part,
                                                    unsigned short* __restrict__ ht) {
    __shared__ unsigned short T[64 * 66];
    __shared__ float sstat[4];   // mean0, rstd0, mean1, rstd1
    int b = blockIdx.z, c0 = blockIdx.y * 64, p0 = blockIdx.x * 64;
    int t = threadIdx.x;
    if (t < 64) {
        int half = t >> 5;                       // group within this c-tile
        int g = b * NG + (c0 >> 5) + half;
        float2 v = part[g * 32 + (t & 31)];
        float s = v.x, ss = v.y;
        #pragma unroll
        for (int off = 16; off > 0; off >>= 1) {
            s  += __shfl_xor(s, off);
            ss += __shfl_xor(ss, off);
        }
        if ((t & 31) == 0) {
            const float inv = 1.f / (float)(CPG * HW);
            float mean = s * inv;
            float var  = ss * inv - mean * mean;
            sstat[half * 2]     = mean;
            sstat[half * 2 + 1] = rsqrtf(var + EPS);
        }
    }
    __syncthreads();
    int cr = t >> 4, pc = t & 15;
    #pragma unroll
    for (int cp = 0; cp < 4; cp++) {
        int c = c0 + cp * 16 + cr;
        int gl = (cp * 16 + cr) >> 5;
        float mean = sstat[gl * 2], rstd = sstat[gl * 2 + 1];
        float sc = gamma[c] * rstd;
        float sh = beta[c] - mean * sc;
        float4 v = *(const float4*)(x + ((size_t)(b * C_ + c)) * HW + p0 + pc * 4);
        int cc = cp * 16 + cr;
        T[(pc*4 + 0) * 66 + cc] = f2bf(v.x*sc + sh);
        T[(pc*4 + 1) * 66 + cc] = f2bf(v.y*sc + sh);
        T[(pc*4 + 2) * 66 + cc] = f2bf(v.z*sc + sh);
        T[(pc*4 + 3) * 66 + cc] = f2bf(v.w*sc + sh);
    }
    __syncthreads();
    int p = t >> 2, cq = t & 3;
    const unsigned* rp = (const unsigned*)(T + p * 66 + cq * 16);
    unsigned short* dst = ht + ((size_t)b * HW + p0 + p) * 256 + c0 + cq * 16;
    *(uint4*)dst       = make_uint4(rp[0], rp[1], rp[2], rp[3]);
    *(uint4*)(dst + 8) = make_uint4(rp[4], rp[5], rp[6], rp[7]);
}

// ---------------- QKV GEMM v2: 128x128 tile, ring-3 LDS staging, counted vmcnt ----------------
// Q/K epilogue: direct uint2 stores (R11's LDS round-trip regressed +8us; L2
// write-combining absorbs 8B/lane scattered stores — revert to R10 form).
__global__ __launch_bounds__(256) void gemm_qkv_mfma_k(const unsigned short* __restrict__ wt,
                                                       const unsigned short* __restrict__ ht,
                                                       const float* __restrict__ bias,
                                                       unsigned short* __restrict__ qt,
                                                       unsigned short* __restrict__ kt,
                                                       unsigned short* __restrict__ vv) {
    __shared__ __align__(16) unsigned short smem[24576];   // ring-3 x (A 8KB + B 8KB) = 48KB
    int t = threadIdx.x, wave = t >> 6, lane = t & 63, quad = lane >> 4, l16 = lane & 15;
    int mq = wave & 1, pq = wave >> 1;
    int L = blockIdx.x;
    int W = (L & 7) * 96 + (L >> 3);          // 768 % 8 == 0: bijective XCD swizzle
    int b = W / 192;
    int rem = W - b * 192;
    int px = rem / 6;
    int my = rem - px * 6;
    const char* Ag = (const char*)(wt + (size_t)(my * 128) * 256);
    const char* Bg = (const char*)(ht + ((size_t)b * HW + px * 128) * 256);

    int soff[2], lbs[2];
    #pragma unroll
    for (int n = 0; n < 2; n++) {
        int s = n * 256 + t;
        int row = s >> 2, c = (s & 3) ^ (row & 3);
        soff[n] = row * 512 + c * 16;          // bytes (global row = 256 bf16 = 512B)
        lbs[n]  = s * 8;                       // ushort idx (slot s -> s*16 bytes)
    }

    auto STAGE = [&](int kc, int buf) {
        const char* a  = Ag + kc * 64;
        const char* bb = Bg + kc * 64;
        #pragma unroll
        for (int n = 0; n < 2; n++) {
            __builtin_amdgcn_global_load_lds((g_void*)(a  + soff[n]), (l_void*)(smem + buf * 8192 + lbs[n]), 16, 0, 0);
            __builtin_amdgcn_global_load_lds((g_void*)(bb + soff[n]), (l_void*)(smem + buf * 8192 + 4096 + lbs[n]), 16, 0, 0);
        }
    };

    f32x4_t acc[4][4];
    const f32x4_t zz = {0.f, 0.f, 0.f, 0.f};
    #pragma unroll
    for (int i = 0; i < 4; i++)
        #pragma unroll
        for (int j = 0; j < 4; j++) acc[i][j] = zz;

    STAGE(0, 0);
    STAGE(1, 1);
    int cur = 0;
    for (int kc = 0; kc < 8; kc++) {
        if (kc < 7) asm volatile("s_waitcnt vmcnt(4)" ::: "memory");
        else        asm volatile("s_waitcnt vmcnt(0)" ::: "memory");
        asm volatile("s_barrier" ::: "memory");
        if (kc + 2 < 8) { int nb = cur + 2; if (nb >= 3) nb -= 3; STAGE(kc + 2, nb); }
        const unsigned short* Ac = smem + cur * 8192;
        const unsigned short* Bc = smem + cur * 8192 + 4096;
        bf16x8_t af[4], bfr[4];
        #pragma unroll
        for (int mi = 0; mi < 4; mi++) {
            int R = mq * 64 + mi * 16 + l16;
            af[mi] = *(const bf16x8_t*)&Ac[(R * 4 + (quad ^ (R & 3))) * 8];
        }
        #pragma unroll
        for (int pi = 0; pi < 4; pi++) {
            int P = pq * 64 + pi * 16 + l16;
            bfr[pi] = *(const bf16x8_t*)&Bc[(P * 4 + (quad ^ (P & 3))) * 8];
        }
        __builtin_amdgcn_s_setprio(1);
        #pragma unroll
        for (int mi = 0; mi < 4; mi++)
            #pragma unroll
            for (int pi = 0; pi < 4; pi++)
                acc[mi][pi] = __builtin_amdgcn_mfma_f32_16x16x32_bf16(af[mi], bfr[pi], acc[mi][pi], 0, 0, 0);
        __builtin_amdgcn_s_setprio(0);
        cur = (cur + 1 == 3) ? 0 : cur + 1;
    }

    int sec = my >> 1;                          // 0=Q 1=K 2=V
    int hh = ((my & 1) << 1) | mq;              // head for Q/K sections
    if (sec < 2) {
        float scl = (sec == 0) ? QSCALE : 1.f;
        unsigned short* dst = ((sec == 0) ? qt : kt) + (size_t)(b * NH + hh) * HW * 64;
        #pragma unroll
        for (int mi = 0; mi < 4; mi++) {
            int d0 = mi * 16 + quad * 4;
            int mg = my * 128 + mq * 64 + d0;
            #pragma unroll
            for (int pi = 0; pi < 4; pi++) {
                int p = px * 128 + pq * 64 + pi * 16 + l16;
                unsigned lo = cvtpk((acc[mi][pi][0] + bias[mg + 0]) * scl,
                                    (acc[mi][pi][1] + bias[mg + 1]) * scl);
                unsigned hi = cvtpk((acc[mi][pi][2] + bias[mg + 2]) * scl,
                                    (acc[mi][pi][3] + bias[mg + 3]) * scl);
                *(uint2*)(dst + (size_t)p * 64 + d0) = make_uint2(lo, hi);
            }
        }
    } else {
        // V: [128 d][128 p] LDS transpose (pitch 130), then coalesced row writes
        __syncthreads();                        // ring buffers fully consumed
        unsigned short* T = smem;
        #pragma unroll
        for (int mi = 0; mi < 4; mi++) {
            int dT = mq * 64 + mi * 16 + quad * 4;
            int mg = my * 128 + dT;
            #pragma unroll
            for (int pi = 0; pi < 4; pi++) {
                int pl = pq * 64 + pi * 16 + l16;
                #pragma unroll
                for (int r = 0; r < 4; r++)
                    T[(dT + r) * 130 + pl] = f2bf(acc[mi][pi][r] + bias[mg + r]);
            }
        }
        __syncthreads();
        int dT = t >> 1, half = t & 1;
        const unsigned* rp = (const unsigned*)(T + dT * 130 + half * 64);
        unsigned short* dd = vv + ((size_t)(b * 256 + (my & 1) * 128 + dT)) * HW + px * 128 + half * 64;
        #pragma unroll
        for (int q8 = 0; q8 < 8; q8++)
            *(uint4*)(dd + q8 * 8) = make_uint4(rp[q8*4+0], rp[q8*4+1], rp[q8*4+2], rp[q8*4+3]);
    }
}

// ---------------- proj GEMM v2: 128x128 tile, ring-3 LDS staging (same skeleton) ----------------
// out[b][256,4096] = wpt[256,256] . ao[b][4096,256]^T + bias + x. Grid 256 blocks.
__global__ __launch_bounds__(256) void gemm_proj_mfma_k(const unsigned short* __restrict__ wpt,
                                                        const unsigned short* __restrict__ ao,
                                                        const float* __restrict__ bias,
                                                        const float* __restrict__ x,
                                                        float* __restrict__ out) {
    __shared__ __align__(16) unsigned short smem[24576];   // ring-3 x (A 8KB + B 8KB) = 48KB
    int t = threadIdx.x, wave = t >> 6, lane = t & 63, quad = lane >> 4, l16 = lane & 15;
    int mq = wave & 1, pq = wave >> 1;
    int L = blockIdx.x;
    int W = (L & 7) * 32 + (L >> 3);          // 256 % 8 == 0: bijective XCD swizzle
    int b = W >> 6;
    int rem = W & 63;
    int px = rem >> 1;
    int my = rem & 1;
    const char* Ag = (const char*)(wpt + (size_t)(my * 128) * 256);
    const char* Bg = (const char*)(ao + ((size_t)b * HW + px * 128) * 256);

    int soff[2], lbs[2];
    #pragma unroll
    for (int n = 0; n < 2; n++) {
        int s = n * 256 + t;
        int row = s >> 2, c = (s & 3) ^ (row & 3);
        soff[n] = row * 512 + c * 16;
        lbs[n]  = s * 8;
    }

    auto STAGE = [&](int kc, int buf) {
        const char* a  = Ag + kc * 64;
        const char* bb = Bg + kc * 64;
        #pragma unroll
        for (int n = 0; n < 2; n++) {
            __builtin_amdgcn_global_load_lds((g_void*)(a  + soff[n]), (l_void*)(smem + buf * 8192 + lbs[n]), 16, 0, 0);
            __builtin_amdgcn_global_load_lds((g_void*)(bb + soff[n]), (l_void*)(smem + buf * 8192 + 4096 + lbs[n]), 16, 0, 0);
        }
    };

    f32x4_t acc[4][4];
    const f32x4_t zz = {0.f, 0.f, 0.f, 0.f};
    #pragma unroll
    for (int i = 0; i < 4; i++)
        #pragma unroll
        for (int j = 0; j < 4; j++) acc[i][j] = zz;

    STAGE(0, 0);
    STAGE(1, 1);
    int cur = 0;
    for (int kc = 0; kc < 8; kc++) {
        if (kc < 7) asm volatile("s_waitcnt vmcnt(4)" ::: "memory");
        else        asm volatile("s_waitcnt vmcnt(0)" ::: "memory");
        asm volatile("s_barrier" ::: "memory");
        if (kc + 2 < 8) { int nb = cur + 2; if (nb >= 3) nb -= 3; STAGE(kc + 2, nb); }
        const unsigned short* Ac = smem + cur * 8192;
        const unsigned short* Bc = smem + cur * 8192 + 4096;
        bf16x8_t af[4], bfr[4];
        #pragma unroll
        for (int mi = 0; mi < 4; mi++) {
            int R = mq * 64 + mi * 16 + l16;
            af[mi] = *(const bf16x8_t*)&Ac[(R * 4 + (quad ^ (R & 3))) * 8];
        }
        #pragma unroll
        for (int pi = 0; pi < 4; pi++) {
            int P = pq * 64 + pi * 16 + l16;
            bfr[pi] = *(const bf16x8_t*)&Bc[(P * 4 + (quad ^ (P & 3))) * 8];
        }
        __builtin_amdgcn_s_setprio(1);
        #pragma unroll
        for (int mi = 0; mi < 4; mi++)
            #pragma unroll
            for (int pi = 0; pi < 4; pi++)
                acc[mi][pi] = __builtin_amdgcn_mfma_f32_16x16x32_bf16(af[mi], bfr[pi], acc[mi][pi], 0, 0, 0);
        __builtin_amdgcn_s_setprio(0);
        cur = (cur + 1 == 3) ? 0 : cur + 1;
    }

    // epilogue: acc + bias + residual x -> fp32 out (lanes contiguous in p: coalesced)
    #pragma unroll
    for (int mi = 0; mi < 4; mi++)
        #pragma unroll
        for (int pi = 0; pi < 4; pi++) {
            int p = px * 128 + pq * 64 + pi * 16 + l16;
            #pragma unroll
            for (int r = 0; r < 4; r++) {
                int m = my * 128 + mq * 64 + mi * 16 + quad * 4 + r;
                size_t off = (size_t)(b * C_ + m) * HW + p;
                out[off] = acc[mi][pi][r] + bias[m] + x[off];
            }
        }
}

// ---------------- Flash attention (unchanged from R8: bounded-score softmax) ----------------
__global__ __launch_bounds__(512) __attribute__((amdgpu_waves_per_eu(2, 8)))
void attn_k(const unsigned short* __restrict__ qt,
            const unsigned short* __restrict__ kt,
            const unsigned short* __restrict__ vv,
            unsigned short* __restrict__ ao) {
    __shared__ __align__(16) unsigned short smem[24576];
    int t = threadIdx.x;
    int wave = t >> 6, lane = t & 63, quad = lane >> 4, l16 = lane & 15;
    int iw = wave & 3, jw = wave >> 2;
    int L = blockIdx.x;
    int W = (L & 7) * 64 + (L >> 3);
    int i0 = (W & 31) * 128;
    int hh = (W >> 5) & 3;
    int b  = W >> 7;
    const unsigned short* qb = qt + (size_t)(b * NH + hh) * HW * 64;
    const char* kbp = (const char*)(kt + (size_t)(b * NH + hh) * HW * 64);
    const char* vbp = (const char*)(vv + (size_t)(b * NH + hh) * 64 * HW);

    bf16x8_t qf[2][2];
    #pragma unroll
    for (int mi = 0; mi < 2; mi++)
        #pragma unroll
        for (int kc = 0; kc < 2; kc++)
            qf[mi][kc] = *(const bf16x8_t*)(qb + (size_t)(i0 + iw * 32 + mi * 16 + l16) * 64 + kc * 32 + quad * 8);

    f32x4_t oacc[4][2], osum[2];
    const f32x4_t zz = {0.f, 0.f, 0.f, 0.f};
    #pragma unroll
    for (int dt = 0; dt < 4; dt++) { oacc[dt][0] = zz; oacc[dt][1] = zz; }
    osum[0] = zz; osum[1] = zz;

    bf16x8_t ones;
    #pragma unroll
    for (int e = 0; e < 8; e++) ones[e] = (short)0x3F80;   // bf16 1.0

    bool isK = (jw == 0);
    int soff[2], lbase[2];
    #pragma unroll
    for (int n = 0; n < 2; n++) {
        int s = (iw * 2 + n) * 64 + lane;
        int row = s >> 3;
        int c = (s & 7) ^ (row & 7);
        soff[n] = isK ? (row * 128 + c * 16) : (row * (HW * 2) + c * 16);
        lbase[n] = (isK ? 0 : 12288) + (iw * 2 + n) * 512;
    }
    const char* gsrc0 = isK ? kbp : vbp;
    int tstride = isK ? 8192 : 128;

    auto STAGE = [&](int tile, int buf) {
        const char* g = gsrc0 + (size_t)tile * tstride;
        #pragma unroll
        for (int n = 0; n < 2; n++)
            __builtin_amdgcn_global_load_lds((g_void*)(g + soff[n]),
                                             (l_void*)(smem + buf * 4096 + lbase[n]), 16, 0, 0);
    };

    STAGE(0, 0);
    STAGE(1, 1);

    int cur = 0;
    for (int jt = 0; jt < 64; jt++) {
        if (jt < 63) asm volatile("s_waitcnt vmcnt(2)" ::: "memory");
        else         asm volatile("s_waitcnt vmcnt(0)" ::: "memory");
        asm volatile("s_barrier" ::: "memory");
        if (jt + 2 < 64) {
            int nb = cur + 2; if (nb >= 3) nb -= 3;
            STAGE(jt + 2, nb);
        }
        const unsigned short* Kc = smem + cur * 4096;
        const unsigned short* Vc = smem + 12288 + cur * 4096;

        f32x4_t sacc[2][2];
        sacc[0][0] = zz; sacc[0][1] = zz; sacc[1][0] = zz; sacc[1][1] = zz;
        __builtin_amdgcn_s_setprio(1);
        #pragma unroll
        for (int nj = 0; nj < 2; nj++) {
            int j = jw * 32 + nj * 16 + l16;
            int rb = j * 8;
            bf16x8_t kf0 = *(const bf16x8_t*)&Kc[(rb + ((quad    ) ^ (j & 7))) * 8];
            bf16x8_t kf1 = *(const bf16x8_t*)&Kc[(rb + ((4 + quad) ^ (j & 7))) * 8];
            #pragma unroll
            for (int mi = 0; mi < 2; mi++) {
                sacc[mi][nj] = __builtin_amdgcn_mfma_f32_16x16x32_bf16(kf0, qf[mi][0], sacc[mi][nj], 0, 0, 0);
                sacc[mi][nj] = __builtin_amdgcn_mfma_f32_16x16x32_bf16(kf1, qf[mi][1], sacc[mi][nj], 0, 0, 0);
            }
        }
        __builtin_amdgcn_s_setprio(0);

        bf16x8_t pf[2];
        #pragma unroll
        for (int mi = 0; mi < 2; mi++) {
            #pragma unroll
            for (int nj = 0; nj < 2; nj++)
                #pragma unroll
                for (int r = 0; r < 4; r++)
                    sacc[mi][nj][r] = __builtin_amdgcn_exp2f(sacc[mi][nj][r]);

            unsigned lo0 = cvtpk(sacc[mi][0][0], sacc[mi][0][1]);
            unsigned hi0 = cvtpk(sacc[mi][0][2], sacc[mi][0][3]);
            unsigned lo1 = cvtpk(sacc[mi][1][0], sacc[mi][1][1]);
            unsigned hi1 = cvtpk(sacc[mi][1][2], sacc[mi][1][3]);
            plswap32(lo0, lo1); plswap16(lo0, lo1);  // lo0=d0, lo1=d2
            plswap32(hi0, hi1); plswap16(hi0, hi1);  // hi0=d1, hi1=d3
            union { unsigned u[4]; bf16x8_t v8; } pu;
            pu.u[0] = lo0; pu.u[1] = hi0; pu.u[2] = lo1; pu.u[3] = hi1;
            pf[mi] = pu.v8;
        }

        __builtin_amdgcn_s_setprio(1);
        #pragma unroll
        for (int dt = 0; dt < 4; dt++) {
            int d = dt * 16 + l16;
            bf16x8_t vf = *(const bf16x8_t*)&Vc[(d * 8 + ((jw * 4 + quad) ^ (d & 7))) * 8];
            oacc[dt][0] = __builtin_amdgcn_mfma_f32_16x16x32_bf16(vf, pf[0], oacc[dt][0], 0, 0, 0);
            oacc[dt][1] = __builtin_amdgcn_mfma_f32_16x16x32_bf16(vf, pf[1], oacc[dt][1], 0, 0, 0);
        }
        osum[0] = __builtin_amdgcn_mfma_f32_16x16x32_bf16(ones, pf[0], osum[0], 0, 0, 0);
        osum[1] = __builtin_amdgcn_mfma_f32_16x16x32_bf16(ones, pf[1], osum[1], 0, 0, 0);
        __builtin_amdgcn_s_setprio(0);

        cur = (cur + 1 == 3) ? 0 : cur + 1;
    }

    __syncthreads();
    float* Obuf = (float*)smem;                // [128 rows][pitch 68]: cols 0..63 = d, 64 = l
    if (jw == 1) {
        #pragma unroll
        for (int mi = 0; mi < 2; mi++) {
            int R = iw * 32 + mi * 16 + l16;
            #pragma unroll
            for (int dt = 0; dt < 4; dt++)
                *(f32x4_t*)&Obuf[R * 68 + dt * 16 + quad * 4] = oacc[dt][mi];
            if (quad == 0)
                Obuf[R * 68 + 64] = osum[mi][0];
        }
    }
    __syncthreads();
    if (jw == 0) {
        #pragma unroll
        for (int mi = 0; mi < 2; mi++) {
            int R = iw * 32 + mi * 16 + l16;
            float l  = osum[mi][0] + Obuf[R * 68 + 64];
            float c0 = 1.f / l;
            unsigned short* dst = ao + ((size_t)b * HW + i0 + R) * 256 + hh * 64 + quad * 4;
            #pragma unroll
            for (int dt = 0; dt < 4; dt++) {
                f32x4_t o1 = *(const f32x4_t*)&Obuf[R * 68 + dt * 16 + quad * 4];
                unsigned w0 = cvtpk((oacc[dt][mi][0] + o1[0]) * c0,
                                    (oacc[dt][mi][1] + o1[1]) * c0);
                unsigned w1 = cvtpk((oacc[dt][mi][2] + o1[2]) * c0,
                                    (oacc[dt][mi][3] + o1[3]) * c0);
                *(uint2*)(dst + dt * 16) = make_uint2(w0, w1);
            }
        }
    }
}

extern "C" void kernel_launch(void* const* d_in, const int* in_sizes, int n_in,
                              void* d_out, int out_size, void* d_ws, size_t ws_size,
                              hipStream_t stream) {
    const float* x      = (const float*)d_in[0];
    const float* gamma  = (const float*)d_in[1];
    const float* beta   = (const float*)d_in[2];
    const float* w_qkv  = (const float*)d_in[3];
    const float* b_qkv  = (const float*)d_in[4];
    const float* w_proj = (const float*)d_in[5];
    const float* b_proj = (const float*)d_in[6];
    float* out = (float*)d_out;

    // ws: stats 256f | part 1024 float2 | ht,qt,kt,vv,ao (5 x 4M ushorts = 40MB) | wt,wpt bf16
    float* stats = (float*)d_ws;
    float2* part = (float2*)(stats + 256);
    unsigned short* ht  = (unsigned short*)(stats + 256 + 2048);
    unsigned short* qt  = ht + (size_t)4194304;
    unsigned short* kt  = qt + (size_t)4194304;
    unsigned short* vv  = kt + (size_t)4194304;
    unsigned short* ao  = vv + (size_t)4194304;
    unsigned short* wt  = ao + (size_t)4194304;
    unsigned short* wpt = wt + 196608;

    gn_stats_wconv_k<<<1280, 256, 0, stream>>>(x, part, w_qkv, w_proj, wt, wpt);
    gn_apply_t_k<<<dim3(64, 4, NB), 256, 0, stream>>>(x, gamma, beta, part, ht);
    gemm_qkv_mfma_k<<<768, 256, 0, stream>>>(wt, ht, b_qkv, qt, kt, vv);
    attn_k<<<512, 512, 0, stream>>>(qt, kt, vv, ao);
    gemm_proj_mfma_k<<<256, 256, 0, stream>>>(wpt, ao, b_proj, x, out);
}